// Round 4
// baseline (446.368 us; speedup 1.0000x reference)
//
#include <hip/hip_runtime.h>
#include <math.h>

#define WP_ 63
#define NPATCH 3969
#define PI_D 3.141592653589793
#define TWO_PI_D 6.283185307179586476925287

// numpy remainder(v, 2pi): fmod then fix sign
__device__ __forceinline__ double remtp_d(double v) {
  double r = fmod(v, TWO_PI_D);
  if (r < 0.0) r += TWO_PI_D;
  return r;
}

// np.linspace(-1,1,8): y = i*step + start (two roundings), y[-1]=stop exact
__device__ __forceinline__ double lin8d(int i) {
  if (i == 7) return 1.0;
  return __dadd_rn(__dmul_rn((double)i, 2.0 / 7.0), -1.0);
}
// np.linspace(0,2pi,32)[:31]: i*step (+0.0 exact)
__device__ __forceinline__ double angd(int n) {
  return __dmul_rn((double)n, TWO_PI_D / 31.0);
}
// np.linspace(-3,3,31): i*0.2 + (-3), y[-1]=3 exact
__device__ __forceinline__ double xyd(int n) {
  if (n == 30) return 3.0;
  return __dadd_rn(__dmul_rn((double)n, 6.0 / 30.0), -3.0);
}

struct JPd {
  double s1, c1, s2, c2, s3, c3, s4, c4;
  double sg13, sg42, gt13, gt42;
};

__device__ JPd jprep_d(double p0, double p1, double p2) {
#pragma clang fp contract(off)
  double r0 = remtp_d(p0), r1 = remtp_d(p1), r2 = remtp_d(p2);
  double mn = fmin(r0, r1), mx = fmax(r0, r1);
  double a1 = fmin(mn, r2);
  double a3 = fmax(mx, r2);
  double a2 = fmax(mn, fmin(mx, r2));  // exact 3-sort median
  double remm = remtp_d(0.5 * (a1 - a3));
  double a4 = 0.5 * (a1 + a3) + ((remm >= PI_D) ? PI_D : 0.0);
  JPd j;
  double r42 = remtp_d(a2 - a4);
  j.sg42 = (r42 < PI_D) ? 1.0 : -1.0;
  j.gt42 = pow(r42 / PI_D - 1.0, 35.0) * 0.1;
  double r13 = remtp_d(a3 - a1);
  j.sg13 = (r13 < PI_D) ? 1.0 : -1.0;
  j.gt13 = pow(r13 / PI_D - 1.0, 35.0) * 0.1;
  j.s1 = sin(a1); j.c1 = cos(a1);
  j.s2 = sin(a2); j.c2 = cos(a2);
  j.s3 = sin(a3); j.c3 = cos(a3);
  j.s4 = sin(a4); j.c4 = cos(a4);
  return j;
}

// distances + wedge weights, mirroring np op order exactly
__device__ __forceinline__ void jdw_d(const JPd& j, double dx, double dy,
                                      double& d13, double& d42,
                                      double& w0, double& w1, double& w2) {
#pragma clang fp contract(off)
  double hl1 = (-j.s1) * dx + j.c1 * dy;
  double hl2 = (-j.s2) * dx + j.c2 * dy;
  double hl3 = (-j.s3) * dx + j.c3 * dy;
  double hl4 = (-j.s4) * dx + j.c4 * dy;
  d13 = j.sg13 * fmin(j.sg13 * hl1, (-j.sg13) * hl3) + j.gt13;
  d42 = j.sg42 * fmin(j.sg42 * hl4, (-j.sg42) * hl2) + j.gt42;
  double h1 = 0.5 * (1.0 + (2.0 / PI_D) * atan(d13 / 0.01));
  double h2 = 0.5 * (1.0 + (2.0 / PI_D) * atan(d42 / 0.01));
  w0 = 1.0 - h1;
  w1 = h1 * (1.0 - h2);
  w2 = h1 * h2;
}

// ---------------- Kernel A: coordinate descent (float64) ----------------
// 1 wave = 2 patches; lane = candidate within each 32-lane half.
__global__ void __launch_bounds__(64) foj_descent(const float* __restrict__ x,
                                                  double* __restrict__ pout) {
  const int lane = threadIdx.x;
  const int half = lane >> 5;
  const int cand = lane & 31;
  const int pair = blockIdx.x;

  __shared__ float4 simg[2][64];
  {
    float* sb = (float*)simg;
    for (int idx = lane; idx < 512; idx += 64) {
      int h2 = idx >> 8;
      int r = idx & 255;
      int px = r >> 2;
      int c = r & 3;
      int patch2 = pair * 2 + h2;
      float v = 0.0f;
      if (c < 3 && patch2 < NPATCH) {
        int ph = patch2 / WP_;
        int pw = patch2 - ph * WP_;
        v = x[c * 65536 + (ph * 4 + (px >> 3)) * 256 + (pw * 4 + (px & 7))];
      }
      sb[idx] = v;
    }
  }
  __syncthreads();
  const float4* sp = simg[half];

  double q0 = 0.0, q1 = 0.0, q2 = 0.0, q3 = 0.0, q4 = 0.0;

#pragma unroll 1
  for (int i = 0; i < 5; ++i) {
#pragma clang fp contract(off)
    double rv = (i < 3) ? angd(cand) : xyd(cand);
    double p0 = q0 + ((i == 0) ? rv : 0.0);
    double p1 = q1 + ((i == 1) ? rv : 0.0);
    double p2 = q2 + ((i == 2) ? rv : 0.0);
    double x0 = q3 + ((i == 3) ? rv : 0.0);
    double y0 = q4 + ((i == 4) ? rv : 0.0);

    JPd j = jprep_d(p0, p1, p2);
    double dxs[8], dys[8];
#pragma unroll
    for (int t = 0; t < 8; ++t) { dxs[t] = lin8d(t) - x0; dys[t] = lin8d(t) - y0; }

    // pass 1: den + num
    double den0 = 0, den1 = 0, den2 = 0;
    double n00 = 0, n01 = 0, n02 = 0, n10 = 0, n11 = 0, n12 = 0;
    double n20 = 0, n21 = 0, n22 = 0;
#pragma unroll 1
    for (int pi2 = 0; pi2 < 8; ++pi2) {
      double dy = dys[pi2];
#pragma unroll
      for (int pj = 0; pj < 8; ++pj) {
        double d13, d42, w0, w1, w2;
        jdw_d(j, dxs[pj], dy, d13, d42, w0, w1, w2);
        float4 im = sp[pi2 * 8 + pj];
        double ix = (double)im.x, iy = (double)im.y, iz = (double)im.z;
        den0 += w0; den1 += w1; den2 += w2;
        n00 += ix * w0; n01 += ix * w1; n02 += ix * w2;
        n10 += iy * w0; n11 += iy * w1; n12 += iy * w2;
        n20 += iz * w0; n21 += iz * w1; n22 += iz * w2;
      }
    }
    double e0 = den0 + 1e-10, e1 = den1 + 1e-10, e2 = den2 + 1e-10;
    double c00 = n00 / e0, c01 = n01 / e1, c02 = n02 / e2;
    double c10 = n10 / e0, c11 = n11 / e1, c12 = n12 / e2;
    double c20 = n20 / e0, c21 = n21 / e1, c22 = n22 / e2;

    // pass 2: direct residual loss (matches np's formula, noise ~1e-15 rel)
    double loss = 0.0;
#pragma unroll 1
    for (int pi2 = 0; pi2 < 8; ++pi2) {
      double dy = dys[pi2];
#pragma unroll
      for (int pj = 0; pj < 8; ++pj) {
        double d13, d42, w0, w1, w2;
        jdw_d(j, dxs[pj], dy, d13, d42, w0, w1, w2);
        float4 im = sp[pi2 * 8 + pj];
        double pv0 = w0 * c00 + w1 * c01 + w2 * c02;
        double pv1 = w0 * c10 + w1 * c11 + w2 * c12;
        double pv2 = w0 * c20 + w1 * c21 + w2 * c22;
        double r0 = (double)im.x - pv0;
        double r1 = (double)im.y - pv1;
        double r2v = (double)im.z - pv2;
        loss += r0 * r0; loss += r1 * r1; loss += r2v * r2v;
      }
    }

    // argmin over 31 candidates, first-index tie-break (np.argmin)
    double bl = (cand < 31) ? loss : (double)INFINITY;
    int bi = cand;
#pragma unroll
    for (int m = 1; m <= 16; m <<= 1) {
      double ol = __shfl_xor(bl, m);
      int oi = __shfl_xor(bi, m);
      if (ol < bl || (ol == bl && oi < bi)) { bl = ol; bi = oi; }
    }
    double upd = (i < 3) ? angd(bi) : xyd(bi);
    if (i == 0) q0 += upd;
    else if (i == 1) q1 += upd;
    else if (i == 2) q2 += upd;
    else if (i == 3) q3 += upd;
    else q4 += upd;
  }

  int patch = pair * 2 + half;
  if (cand == 0 && patch < NPATCH) {
    pout[patch * 5 + 0] = q0;
    pout[patch * 5 + 1] = q1;
    pout[patch * 5 + 2] = q2;
    pout[patch * 5 + 3] = q3;
    pout[patch * 5 + 4] = q4;
  }
}

// ---------------- Kernel B: final reconstruction + fold (atomic) --------
__global__ void __launch_bounds__(256) foj_final(const float* __restrict__ x,
                                                 const double* __restrict__ pin,
                                                 float* __restrict__ out) {
#pragma clang fp contract(off)
  int lane = threadIdx.x & 63;
  int patch = blockIdx.x * 4 + (threadIdx.x >> 6);
  if (patch >= NPATCH) return;
  int ph = patch / WP_;
  int pw = patch - ph * WP_;
  double q0 = pin[patch * 5 + 0];
  double q1 = pin[patch * 5 + 1];
  double q2 = pin[patch * 5 + 2];
  double x0 = pin[patch * 5 + 3];
  double y0 = pin[patch * 5 + 4];

  JPd j = jprep_d(q0, q1, q2);
  int pi2 = lane >> 3, pj = lane & 7;
  double dx = lin8d(pj) - x0;
  double dy = lin8d(pi2) - y0;
  double d13, d42, w0, w1, w2;
  jdw_d(j, dx, dy, d13, d42, w0, w1, w2);

  int oy = ph * 4 + pi2, ox = pw * 4 + pj;
  double im0 = (double)x[oy * 256 + ox];
  double im1 = (double)x[65536 + oy * 256 + ox];
  double im2 = (double)x[131072 + oy * 256 + ox];

  double red[12] = {w0, w1, w2,
                    im0 * w0, im0 * w1, im0 * w2,
                    im1 * w0, im1 * w1, im1 * w2,
                    im2 * w0, im2 * w1, im2 * w2};
#pragma unroll
  for (int t = 0; t < 12; ++t) {
    double v = red[t];
#pragma unroll
    for (int m = 1; m <= 32; m <<= 1) v += __shfl_xor(v, m);
    red[t] = v;
  }
  double e0 = red[0] + 1e-10, e1 = red[1] + 1e-10, e2 = red[2] + 1e-10;
  double pv0 = w0 * (red[3] / e0) + w1 * (red[4] / e1) + w2 * (red[5] / e2);
  double pv1 = w0 * (red[6] / e0) + w1 * (red[7] / e1) + w2 * (red[8] / e2);
  double pv2 = w0 * (red[9] / e0) + w1 * (red[10] / e1) + w2 * (red[11] / e2);

  double minabs = (d13 < 0.0) ? -d13
                              : ((d42 < 0.0) ? fmin(d13, -d42) : fmin(d13, d42));
  double tb = minabs / 0.05;
  double bnd = 1.0 / (1.0 + tb * tb);

  atomicAdd(&out[oy * 256 + ox], (float)pv0);
  atomicAdd(&out[65536 + oy * 256 + ox], (float)pv1);
  atomicAdd(&out[131072 + oy * 256 + ox], (float)pv2);
  atomicAdd(&out[196608 + oy * 256 + ox], (float)bnd);
}

// ---------------- Kernel C: divide by num_patches -----------------------
__global__ void __launch_bounds__(256) foj_norm(float* __restrict__ out) {
  int idx = blockIdx.x * 256 + threadIdx.x;
  int y = idx >> 8, xx = idx & 255;
  int hlo = (y >= 4) ? ((y - 4) >> 2) : 0;
  int hhi = min(62, y >> 2);
  int wlo = (xx >= 4) ? ((xx - 4) >> 2) : 0;
  int whi = min(62, xx >> 2);
  float np_ = (float)((hhi - hlo + 1) * (whi - wlo + 1));
  out[idx] /= np_;
  out[65536 + idx] /= np_;
  out[131072 + idx] /= np_;
  out[196608 + idx] /= np_;
}

extern "C" void kernel_launch(void* const* d_in, const int* in_sizes, int n_in,
                              void* d_out, int out_size, void* d_ws, size_t ws_size,
                              hipStream_t stream) {
  const float* x = (const float*)d_in[0];
  float* out = (float*)d_out;
  double* pws = (double*)d_ws;  // 3969*5 doubles = ~159 KB scratch

  foj_descent<<<(NPATCH + 1) / 2, 64, 0, stream>>>(x, pws);
  hipMemsetAsync(d_out, 0, (size_t)out_size * sizeof(float), stream);
  foj_final<<<(NPATCH + 3) / 4, 256, 0, stream>>>(x, pws, out);
  foj_norm<<<256, 256, 0, stream>>>(out);
}

// Round 5
// 321.324 us; speedup vs baseline: 1.3892x; 1.3892x over previous
//
#include <hip/hip_runtime.h>
#include <math.h>

#define WP_ 63
#define NPATCH 3969
#define PI_D 3.141592653589793
#define TWO_PI_D 6.283185307179586476925287

// numpy remainder(v, 2pi): fmod then fix sign
__device__ __forceinline__ double remtp_d(double v) {
  double r = fmod(v, TWO_PI_D);
  if (r < 0.0) r += TWO_PI_D;
  return r;
}

// np.linspace(-1,1,8): y = i*step + start (two roundings), y[-1]=stop exact
__device__ __forceinline__ double lin8d(int i) {
  if (i == 7) return 1.0;
  return __dadd_rn(__dmul_rn((double)i, 2.0 / 7.0), -1.0);
}
// np.linspace(0,2pi,32)[:31]: i*step (+0.0 exact)
__device__ __forceinline__ double angd(int n) {
  return __dmul_rn((double)n, TWO_PI_D / 31.0);
}
// np.linspace(-3,3,31): i*0.2 + (-3), y[-1]=3 exact
__device__ __forceinline__ double xyd(int n) {
  if (n == 30) return 3.0;
  return __dadd_rn(__dmul_rn((double)n, 6.0 / 30.0), -3.0);
}

// x^35 LSB-first binary exponentiation: matches numpy npy_pow integer
// fast path grouping ((x*x^2)*x^32), ~10x cheaper than ocml pow.
__device__ __forceinline__ double pow35_d(double x) {
#pragma clang fp contract(off)
  double x2 = x * x;
  double r = x * x2;      // x^3  (bits 0,1)
  double b = x2 * x2;     // x^4
  b = b * b;              // x^8
  b = b * b;              // x^16
  b = b * b;              // x^32
  return r * b;           // x^35 (bit 5)
}

struct JPd {
  double s1, c1, s2, c2, s3, c3, s4, c4;
  double sg13, sg42, gt13, gt42;
};

__device__ JPd jprep_d(double p0, double p1, double p2) {
#pragma clang fp contract(off)
  double r0 = remtp_d(p0), r1 = remtp_d(p1), r2 = remtp_d(p2);
  double mn = fmin(r0, r1), mx = fmax(r0, r1);
  double a1 = fmin(mn, r2);
  double a3 = fmax(mx, r2);
  double a2 = fmax(mn, fmin(mx, r2));  // exact 3-sort median
  double remm = remtp_d(0.5 * (a1 - a3));
  double a4 = 0.5 * (a1 + a3) + ((remm >= PI_D) ? PI_D : 0.0);
  JPd j;
  double r42 = remtp_d(a2 - a4);
  j.sg42 = (r42 < PI_D) ? 1.0 : -1.0;
  j.gt42 = pow35_d(r42 / PI_D - 1.0) * 0.1;
  double r13 = remtp_d(a3 - a1);
  j.sg13 = (r13 < PI_D) ? 1.0 : -1.0;
  j.gt13 = pow35_d(r13 / PI_D - 1.0) * 0.1;
  j.s1 = sin(a1); j.c1 = cos(a1);
  j.s2 = sin(a2); j.c2 = cos(a2);
  j.s3 = sin(a3); j.c3 = cos(a3);
  j.s4 = sin(a4); j.c4 = cos(a4);
  return j;
}

// distances + wedge weights, mirroring np op order exactly
__device__ __forceinline__ void jdw_d(const JPd& j, double dx, double dy,
                                      double& d13, double& d42,
                                      double& w0, double& w1, double& w2) {
#pragma clang fp contract(off)
  double hl1 = (-j.s1) * dx + j.c1 * dy;
  double hl2 = (-j.s2) * dx + j.c2 * dy;
  double hl3 = (-j.s3) * dx + j.c3 * dy;
  double hl4 = (-j.s4) * dx + j.c4 * dy;
  d13 = j.sg13 * fmin(j.sg13 * hl1, (-j.sg13) * hl3) + j.gt13;
  d42 = j.sg42 * fmin(j.sg42 * hl4, (-j.sg42) * hl2) + j.gt42;
  double h1 = 0.5 * (1.0 + (2.0 / PI_D) * atan(d13 / 0.01));
  double h2 = 0.5 * (1.0 + (2.0 / PI_D) * atan(d42 / 0.01));
  w0 = 1.0 - h1;
  w1 = h1 * (1.0 - h2);
  w2 = h1 * h2;
}

// ---------------- Kernel A: coordinate descent (float64, one-pass) -------
// 1 wave = 1 patch. lane = 32*pixel_half + candidate.
// Expanded loss: q = c^T W c - 2 c.n per channel (ssq dropped: constant
// across candidates within a sweep -> argmin invariant).
__global__ void __launch_bounds__(256) foj_descent(const float* __restrict__ x,
                                                   double* __restrict__ pout) {
  const int tid = threadIdx.x;
  const int wv = tid >> 6;      // wave within block: patch select
  const int lane = tid & 63;
  const int hp = lane >> 5;     // pixel half (0: px 0..31, 1: px 32..63)
  const int cand = lane & 31;
  const int patch = blockIdx.x * 4 + wv;

  __shared__ float4 simg[4][64];
  if (patch < NPATCH) {
    int ph = patch / WP_;
    int pw = patch - ph * WP_;
    int py = lane >> 3, pxx = lane & 7;
    int base = (ph * 4 + py) * 256 + (pw * 4 + pxx);
    float4 v;
    v.x = x[base];
    v.y = x[65536 + base];
    v.z = x[131072 + base];
    v.w = 0.0f;
    simg[wv][lane] = v;
  }
  __syncthreads();
  if (patch >= NPATCH) return;
  const float4* sp = simg[wv];

  double q0 = 0.0, q1 = 0.0, q2 = 0.0, q3 = 0.0, q4 = 0.0;

#pragma unroll 1
  for (int i = 0; i < 5; ++i) {
#pragma clang fp contract(off)
    double rv = (i < 3) ? angd(cand) : xyd(cand);
    double p0 = q0 + ((i == 0) ? rv : 0.0);
    double p1 = q1 + ((i == 1) ? rv : 0.0);
    double p2 = q2 + ((i == 2) ? rv : 0.0);
    double x0 = q3 + ((i == 3) ? rv : 0.0);
    double y0 = q4 + ((i == 4) ? rv : 0.0);

    JPd j = jprep_d(p0, p1, p2);
    double dxs[8];
#pragma unroll
    for (int t = 0; t < 8; ++t) dxs[t] = lin8d(t) - x0;
    double dys[4];
#pragma unroll
    for (int r = 0; r < 4; ++r) dys[r] = lin8d(hp * 4 + r) - y0;

    // one pass over this half's 32 pixels: den(3), n(9), W(6)
    double den0 = 0, den1 = 0, den2 = 0;
    double n00 = 0, n01 = 0, n02 = 0, n10 = 0, n11 = 0, n12 = 0;
    double n20 = 0, n21 = 0, n22 = 0;
    double W00 = 0, W01 = 0, W02 = 0, W11 = 0, W12 = 0, W22 = 0;
#pragma unroll 1
    for (int r = 0; r < 4; ++r) {
      double dy = dys[r];
#pragma unroll
      for (int c = 0; c < 8; ++c) {
        double d13, d42, w0, w1, w2;
        jdw_d(j, dxs[c], dy, d13, d42, w0, w1, w2);
        float4 im = sp[hp * 32 + r * 8 + c];
        double ix = (double)im.x, iy = (double)im.y, iz = (double)im.z;
        den0 += w0; den1 += w1; den2 += w2;
        n00 += ix * w0; n01 += ix * w1; n02 += ix * w2;
        n10 += iy * w0; n11 += iy * w1; n12 += iy * w2;
        n20 += iz * w0; n21 += iz * w1; n22 += iz * w2;
        W00 += w0 * w0; W01 += w0 * w1; W02 += w0 * w2;
        W11 += w1 * w1; W12 += w1 * w2; W22 += w2 * w2;
      }
    }
    // combine halves (lane i <-> i+32); f64 add commutative -> both halves
    // hold bit-identical totals
    den0 += __shfl_xor(den0, 32); den1 += __shfl_xor(den1, 32); den2 += __shfl_xor(den2, 32);
    n00 += __shfl_xor(n00, 32); n01 += __shfl_xor(n01, 32); n02 += __shfl_xor(n02, 32);
    n10 += __shfl_xor(n10, 32); n11 += __shfl_xor(n11, 32); n12 += __shfl_xor(n12, 32);
    n20 += __shfl_xor(n20, 32); n21 += __shfl_xor(n21, 32); n22 += __shfl_xor(n22, 32);
    W00 += __shfl_xor(W00, 32); W01 += __shfl_xor(W01, 32); W02 += __shfl_xor(W02, 32);
    W11 += __shfl_xor(W11, 32); W12 += __shfl_xor(W12, 32); W22 += __shfl_xor(W22, 32);

    double e0 = den0 + 1e-10, e1 = den1 + 1e-10, e2 = den2 + 1e-10;
    double c00 = n00 / e0, c01 = n01 / e1, c02 = n02 / e2;
    double c10 = n10 / e0, c11 = n11 / e1, c12 = n12 / e2;
    double c20 = n20 / e0, c21 = n21 / e1, c22 = n22 / e2;

    double loss =
        c00 * (W00 * c00 + W01 * c01 + W02 * c02 - 2.0 * n00) +
        c01 * (W01 * c00 + W11 * c01 + W12 * c02 - 2.0 * n01) +
        c02 * (W02 * c00 + W12 * c01 + W22 * c02 - 2.0 * n02) +
        c10 * (W00 * c10 + W01 * c11 + W02 * c12 - 2.0 * n10) +
        c11 * (W01 * c10 + W11 * c11 + W12 * c12 - 2.0 * n11) +
        c12 * (W02 * c10 + W12 * c11 + W22 * c12 - 2.0 * n12) +
        c20 * (W00 * c20 + W01 * c21 + W02 * c22 - 2.0 * n20) +
        c21 * (W01 * c20 + W11 * c21 + W12 * c22 - 2.0 * n21) +
        c22 * (W02 * c20 + W12 * c21 + W22 * c22 - 2.0 * n22);

    // argmin over 31 candidates, first-index tie-break (np.argmin);
    // both halves hold identical loss -> masks 1..16 suffice
    double bl = (cand < 31) ? loss : (double)INFINITY;
    int bi = cand;
#pragma unroll
    for (int m = 1; m <= 16; m <<= 1) {
      double ol = __shfl_xor(bl, m);
      int oi = __shfl_xor(bi, m);
      if (ol < bl || (ol == bl && oi < bi)) { bl = ol; bi = oi; }
    }
    double upd = (i < 3) ? angd(bi) : xyd(bi);
    if (i == 0) q0 += upd;
    else if (i == 1) q1 += upd;
    else if (i == 2) q2 += upd;
    else if (i == 3) q3 += upd;
    else q4 += upd;
  }

  if (lane == 0) {
    pout[patch * 5 + 0] = q0;
    pout[patch * 5 + 1] = q1;
    pout[patch * 5 + 2] = q2;
    pout[patch * 5 + 3] = q3;
    pout[patch * 5 + 4] = q4;
  }
}

// ---------------- Kernel B: final reconstruction + fold (atomic) --------
__global__ void __launch_bounds__(256) foj_final(const float* __restrict__ x,
                                                 const double* __restrict__ pin,
                                                 float* __restrict__ out) {
#pragma clang fp contract(off)
  int lane = threadIdx.x & 63;
  int patch = blockIdx.x * 4 + (threadIdx.x >> 6);
  if (patch >= NPATCH) return;
  int ph = patch / WP_;
  int pw = patch - ph * WP_;
  double q0 = pin[patch * 5 + 0];
  double q1 = pin[patch * 5 + 1];
  double q2 = pin[patch * 5 + 2];
  double x0 = pin[patch * 5 + 3];
  double y0 = pin[patch * 5 + 4];

  JPd j = jprep_d(q0, q1, q2);
  int pi2 = lane >> 3, pj = lane & 7;
  double dx = lin8d(pj) - x0;
  double dy = lin8d(pi2) - y0;
  double d13, d42, w0, w1, w2;
  jdw_d(j, dx, dy, d13, d42, w0, w1, w2);

  int oy = ph * 4 + pi2, ox = pw * 4 + pj;
  double im0 = (double)x[oy * 256 + ox];
  double im1 = (double)x[65536 + oy * 256 + ox];
  double im2 = (double)x[131072 + oy * 256 + ox];

  double red[12] = {w0, w1, w2,
                    im0 * w0, im0 * w1, im0 * w2,
                    im1 * w0, im1 * w1, im1 * w2,
                    im2 * w0, im2 * w1, im2 * w2};
#pragma unroll
  for (int t = 0; t < 12; ++t) {
    double v = red[t];
#pragma unroll
    for (int m = 1; m <= 32; m <<= 1) v += __shfl_xor(v, m);
    red[t] = v;
  }
  double e0 = red[0] + 1e-10, e1 = red[1] + 1e-10, e2 = red[2] + 1e-10;
  double pv0 = w0 * (red[3] / e0) + w1 * (red[4] / e1) + w2 * (red[5] / e2);
  double pv1 = w0 * (red[6] / e0) + w1 * (red[7] / e1) + w2 * (red[8] / e2);
  double pv2 = w0 * (red[9] / e0) + w1 * (red[10] / e1) + w2 * (red[11] / e2);

  double minabs = (d13 < 0.0) ? -d13
                              : ((d42 < 0.0) ? fmin(d13, -d42) : fmin(d13, d42));
  double tb = minabs / 0.05;
  double bnd = 1.0 / (1.0 + tb * tb);

  atomicAdd(&out[oy * 256 + ox], (float)pv0);
  atomicAdd(&out[65536 + oy * 256 + ox], (float)pv1);
  atomicAdd(&out[131072 + oy * 256 + ox], (float)pv2);
  atomicAdd(&out[196608 + oy * 256 + ox], (float)bnd);
}

// ---------------- Kernel C: divide by num_patches -----------------------
__global__ void __launch_bounds__(256) foj_norm(float* __restrict__ out) {
  int idx = blockIdx.x * 256 + threadIdx.x;
  int y = idx >> 8, xx = idx & 255;
  int hlo = (y >= 4) ? ((y - 4) >> 2) : 0;
  int hhi = min(62, y >> 2);
  int wlo = (xx >= 4) ? ((xx - 4) >> 2) : 0;
  int whi = min(62, xx >> 2);
  float np_ = (float)((hhi - hlo + 1) * (whi - wlo + 1));
  out[idx] /= np_;
  out[65536 + idx] /= np_;
  out[131072 + idx] /= np_;
  out[196608 + idx] /= np_;
}

extern "C" void kernel_launch(void* const* d_in, const int* in_sizes, int n_in,
                              void* d_out, int out_size, void* d_ws, size_t ws_size,
                              hipStream_t stream) {
  const float* x = (const float*)d_in[0];
  float* out = (float*)d_out;
  double* pws = (double*)d_ws;  // 3969*5 doubles = ~159 KB scratch

  foj_descent<<<(NPATCH + 3) / 4, 256, 0, stream>>>(x, pws);
  hipMemsetAsync(d_out, 0, (size_t)out_size * sizeof(float), stream);
  foj_final<<<(NPATCH + 3) / 4, 256, 0, stream>>>(x, pws, out);
  foj_norm<<<256, 256, 0, stream>>>(out);
}